// Round 5
// baseline (708.566 us; speedup 1.0000x reference)
//
#include <hip/hip_runtime.h>
#include <hip/hip_bf16.h>
#include <math.h>

// ---------------------------------------------------------------------------
// ActorGNN: 4-layer GraphConv. R5:
//  - dense: __launch_bounds__(256,2) so the allocator keeps the 128 weight
//    floats in VGPRs (R4's VGPR_Count=72 proved they were being re-fetched
//    per node: ~32KB/node L1 traffic = the 73us). float4-chunk row reads on
//    the scalar (s_load) path, 2 indep acc chains.
//  - dinv fused into gather epilogue (dense drops the load+mul).
// ---------------------------------------------------------------------------

__device__ __forceinline__ int load_idx32(const int* __restrict__ ei32, int is64,
                                          long long pos) {
    return is64 ? ei32[2 * pos] : ei32[pos];
}

// int64 vs int32 edge_index detection (int64 values < 2^31 => odd words zero)
__global__ void detect_idx_kernel(const int* __restrict__ ei, int* __restrict__ flag) {
    int allz = 1;
    for (int i = 0; i < 32; ++i)
        if (ei[2 * i + 1] != 0) allz = 0;
    *flag = allz;
}

__global__ void zero_int_kernel(int* __restrict__ p, int n) {
    int i = blockIdx.x * blockDim.x + threadIdx.x;
    if (i < n) p[i] = 0;
}

__global__ void hist_kernel(const int* __restrict__ ei32, const int* __restrict__ flagp,
                            int* __restrict__ degi, int E) {
    int e = blockIdx.x * blockDim.x + threadIdx.x;
    if (e >= E) return;
    int is64 = *flagp;
    int dst = load_idx32(ei32, is64, (long long)E + e);
    atomicAdd(&degi[dst], 1);
}

// exclusive scan over degi -> off, 1024 elems/block, block sums -> bsum
__global__ __launch_bounds__(256) void scanA_kernel(const int* __restrict__ degi,
                                                    int* __restrict__ off,
                                                    int* __restrict__ bsum, int N) {
    __shared__ int lds[256];
    int t = threadIdx.x;
    int base = blockIdx.x * 1024 + t * 4;
    int d[4];
#pragma unroll
    for (int i = 0; i < 4; ++i) d[i] = (base + i < N) ? degi[base + i] : 0;
    int s = d[0] + d[1] + d[2] + d[3];
    lds[t] = s;
    __syncthreads();
    for (int o = 1; o < 256; o <<= 1) {
        int v = (t >= o) ? lds[t - o] : 0;
        __syncthreads();
        lds[t] += v;
        __syncthreads();
    }
    int excl = lds[t] - s;
    if (t == 255) bsum[blockIdx.x] = lds[255];
    int p = excl;
#pragma unroll
    for (int i = 0; i < 4; ++i) {
        if (base + i < N) off[base + i] = p;
        p += d[i];
    }
}

__global__ __launch_bounds__(1024) void scanB_kernel(int* __restrict__ bsum, int B) {
    __shared__ int lds[1024];
    int t = threadIdx.x;
    int s = (t < B) ? bsum[t] : 0;
    lds[t] = s;
    __syncthreads();
    for (int o = 1; o < 1024; o <<= 1) {
        int v = (t >= o) ? lds[t - o] : 0;
        __syncthreads();
        lds[t] += v;
        __syncthreads();
    }
    if (t < B) bsum[t] = lds[t] - s;
}

__global__ void scanC_kernel(int* __restrict__ off, const int* __restrict__ bsum, int N) {
    int i = blockIdx.x * blockDim.x + threadIdx.x;
    if (i < N) off[i] += bsum[i >> 10];
}

__global__ void copy_int_kernel(int* __restrict__ dstp, const int* __restrict__ srcp, int n) {
    int i = blockIdx.x * blockDim.x + threadIdx.x;
    if (i < n) dstp[i] = srcp[i];
}

// dst-range-partitioned CSR fill (L2 line locality for the scattered writes).
// Afterwards cur[n] == off[n] + deg[n] (used as `end`).
__global__ __launch_bounds__(256) void fill_kernel(const int* __restrict__ ei32,
                                                   const int* __restrict__ flagp,
                                                   int* __restrict__ cur,
                                                   int* __restrict__ col, int E) {
    int r = blockIdx.x & 7;
    int chunk = blockIdx.x >> 3;
    int nchunks = gridDim.x >> 3;
    int is64 = *flagp;
    int stride = nchunks * 256;
    for (int e = chunk * 256 + threadIdx.x; e < E; e += stride) {
        int dst = load_idx32(ei32, is64, (long long)E + e);
        if ((int)(((unsigned)dst * 41u) >> 19) == r) {
            int src = load_idx32(ei32, is64, e);
            int pos = atomicAdd(&cur[dst], 1);
            col[pos] = src;
        }
    }
}

__global__ void deginv_kernel(const int* __restrict__ degi, float* __restrict__ dinv, int N) {
    int n = blockIdx.x * blockDim.x + threadIdx.x;
    if (n < N) dinv[n] = 1.0f / fmaxf((float)degi[n], 1.0f);
}

// wave per node; lane = g*16 + t: edge-group g (0..3), dims t*4..t*4+3.
// Keeps 16 rows in flight per wave. Output pre-scaled by dinv[n].
__global__ __launch_bounds__(256) void gather64_kernel(
    const float* __restrict__ h, const int* __restrict__ off, const int* __restrict__ endp,
    const int* __restrict__ col, const float* __restrict__ dinv,
    float* __restrict__ agg, int N) {
    int wave = threadIdx.x >> 6;
    int lane = threadIdx.x & 63;
    int g = lane >> 4;
    int t = lane & 15;
    int n = blockIdx.x * 4 + wave;
    if (n >= N) return;
    int e = off[n], end = endp[n];
    float4 a0 = make_float4(0.f, 0.f, 0.f, 0.f);
    float4 a1 = make_float4(0.f, 0.f, 0.f, 0.f);
    float4 a2 = make_float4(0.f, 0.f, 0.f, 0.f);
    float4 a3 = make_float4(0.f, 0.f, 0.f, 0.f);
    for (; e + 16 <= end; e += 16) {
        int s0 = col[e + g];
        int s1 = col[e + 4 + g];
        int s2 = col[e + 8 + g];
        int s3 = col[e + 12 + g];
        float4 v0 = *(const float4*)&h[(size_t)s0 * 64 + t * 4];
        float4 v1 = *(const float4*)&h[(size_t)s1 * 64 + t * 4];
        float4 v2 = *(const float4*)&h[(size_t)s2 * 64 + t * 4];
        float4 v3 = *(const float4*)&h[(size_t)s3 * 64 + t * 4];
        a0.x += v0.x; a0.y += v0.y; a0.z += v0.z; a0.w += v0.w;
        a1.x += v1.x; a1.y += v1.y; a1.z += v1.z; a1.w += v1.w;
        a2.x += v2.x; a2.y += v2.y; a2.z += v2.z; a2.w += v2.w;
        a3.x += v3.x; a3.y += v3.y; a3.z += v3.z; a3.w += v3.w;
    }
    for (; e + 8 <= end; e += 8) {
        int s0 = col[e + g];
        int s1 = col[e + 4 + g];
        float4 v0 = *(const float4*)&h[(size_t)s0 * 64 + t * 4];
        float4 v1 = *(const float4*)&h[(size_t)s1 * 64 + t * 4];
        a0.x += v0.x; a0.y += v0.y; a0.z += v0.z; a0.w += v0.w;
        a1.x += v1.x; a1.y += v1.y; a1.z += v1.z; a1.w += v1.w;
    }
    for (; e < end; e += 4) {
        if (e + g < end) {
            int s0 = col[e + g];
            float4 v0 = *(const float4*)&h[(size_t)s0 * 64 + t * 4];
            a2.x += v0.x; a2.y += v0.y; a2.z += v0.z; a2.w += v0.w;
        }
    }
    float4 acc;
    acc.x = (a0.x + a1.x) + (a2.x + a3.x);
    acc.y = (a0.y + a1.y) + (a2.y + a3.y);
    acc.z = (a0.z + a1.z) + (a2.z + a3.z);
    acc.w = (a0.w + a1.w) + (a2.w + a3.w);
#pragma unroll
    for (int m = 16; m <= 32; m <<= 1) {
        acc.x += __shfl_xor(acc.x, m, 64);
        acc.y += __shfl_xor(acc.y, m, 64);
        acc.z += __shfl_xor(acc.z, m, 64);
        acc.w += __shfl_xor(acc.w, m, 64);
    }
    if (g == 0) {
        float di = dinv[n];
        acc.x *= di; acc.y *= di; acc.z *= di; acc.w *= di;
        ((float4*)agg)[(size_t)n * 16 + t] = acc;
    }
}

// out[n,:] = act(h[n,:]@Ws + agg[n,:]@Wn + b); agg pre-scaled by dinv.
// Lane owns out col `lane`; weight columns pinned in VGPRs (launch_bounds
// grants 256 VGPR/wave); rows read on the scalar path (wave-uniform n).
__global__ __launch_bounds__(256, 2) void dense_reg_kernel(
    const float* __restrict__ h, const float* __restrict__ agg,
    const float* __restrict__ Ws, const float* __restrict__ Wn,
    const float* __restrict__ b, float* __restrict__ out, int N, int do_relu) {
    int lane = threadIdx.x & 63;
    int wave_id = (blockIdx.x * blockDim.x + threadIdx.x) >> 6;
    int nwaves = (gridDim.x * blockDim.x) >> 6;
    float ws[64], wn[64];
#pragma unroll
    for (int k = 0; k < 64; ++k) {
        ws[k] = Ws[k * 64 + lane];
        wn[k] = Wn[k * 64 + lane];
    }
    float bl = b[lane];
    for (int n0 = wave_id; n0 < N; n0 += nwaves) {
        int n = __builtin_amdgcn_readfirstlane(n0);
        const float4* hv = (const float4*)(h + (size_t)n * 64);
        const float4* av = (const float4*)(agg + (size_t)n * 64);
        float as0 = 0.f, as1 = 0.f, an0 = 0.f, an1 = 0.f;
#pragma unroll
        for (int c = 0; c < 16; c += 2) {
            float4 hc0 = hv[c], hc1 = hv[c + 1];
            float4 ac0 = av[c], ac1 = av[c + 1];
            as0 = fmaf(hc0.x, ws[4 * c + 0], as0);
            as1 = fmaf(hc0.y, ws[4 * c + 1], as1);
            as0 = fmaf(hc0.z, ws[4 * c + 2], as0);
            as1 = fmaf(hc0.w, ws[4 * c + 3], as1);
            an0 = fmaf(ac0.x, wn[4 * c + 0], an0);
            an1 = fmaf(ac0.y, wn[4 * c + 1], an1);
            an0 = fmaf(ac0.z, wn[4 * c + 2], an0);
            an1 = fmaf(ac0.w, wn[4 * c + 3], an1);
            as0 = fmaf(hc1.x, ws[4 * c + 4], as0);
            as1 = fmaf(hc1.y, ws[4 * c + 5], as1);
            as0 = fmaf(hc1.z, ws[4 * c + 6], as0);
            as1 = fmaf(hc1.w, ws[4 * c + 7], as1);
            an0 = fmaf(ac1.x, wn[4 * c + 4], an0);
            an1 = fmaf(ac1.y, wn[4 * c + 5], an1);
            an0 = fmaf(ac1.z, wn[4 * c + 6], an0);
            an1 = fmaf(ac1.w, wn[4 * c + 7], an1);
        }
        float v = (as0 + as1) + (an0 + an1) + bl;
        if (do_relu) v = fmaxf(v, 0.f);
        out[(size_t)n * 64 + lane] = v;
    }
}

// layer-4 pre-transform: s[n]=h[n,:]·Ws4, g[n]=h[n,:]·Wn4 (64->1)
__global__ __launch_bounds__(256) void layer4_pre_kernel(
    const float* __restrict__ h, const float* __restrict__ Ws,
    const float* __restrict__ Wn, float* __restrict__ s, float* __restrict__ g, int N) {
    int wave = threadIdx.x >> 6;
    int lane = threadIdx.x & 63;
    int n = blockIdx.x * 4 + wave;
    if (n >= N) return;
    float hv = h[(size_t)n * 64 + lane];
    float vs = hv * Ws[lane];
    float vn = hv * Wn[lane];
#pragma unroll
    for (int o = 32; o > 0; o >>= 1) {
        vs += __shfl_down(vs, o, 64);
        vn += __shfl_down(vn, o, 64);
    }
    if (lane == 0) {
        s[n] = vs;
        g[n] = vn;
    }
}

// thread per node: scalar CSR gather of g (400 KB, L2-resident) + sigmoid
__global__ void final_kernel(const float* __restrict__ s, const float* __restrict__ dinv,
                             const float* __restrict__ g, const int* __restrict__ off,
                             const int* __restrict__ endp, const int* __restrict__ col,
                             const float* __restrict__ b4, float* __restrict__ out, int N) {
    int n = blockIdx.x * blockDim.x + threadIdx.x;
    if (n >= N) return;
    float a = 0.f;
    int e = off[n], end = endp[n];
    for (; e < end; ++e) a += g[col[e]];
    float z = s[n] + dinv[n] * a + b4[0];
    out[n] = 1.0f / (1.0f + expf(-z));
}

static inline int cdiv(long long a, long long b) { return (int)((a + b - 1) / b); }

extern "C" void kernel_launch(void* const* d_in, const int* in_sizes, int n_in,
                              void* d_out, int out_size, void* d_ws, size_t ws_size,
                              hipStream_t stream) {
    const float* x   = (const float*)d_in[0];
    const int*   ei  = (const int*)d_in[1];
    const float* Ws1 = (const float*)d_in[2];
    const float* Wn1 = (const float*)d_in[3];
    const float* b1  = (const float*)d_in[4];
    const float* Ws2 = (const float*)d_in[5];
    const float* Wn2 = (const float*)d_in[6];
    const float* b2  = (const float*)d_in[7];
    const float* Ws3 = (const float*)d_in[8];
    const float* Wn3 = (const float*)d_in[9];
    const float* b3  = (const float*)d_in[10];
    const float* Ws4 = (const float*)d_in[11];
    const float* Wn4 = (const float*)d_in[12];
    const float* b4  = (const float*)d_in[13];
    float* out = (float*)d_out;

    const int N = in_sizes[0] / 64;
    const int E = in_sizes[1] / 2;

    // workspace layout
    float* bufA = (float*)d_ws;                   // N*64
    float* bufB = bufA + (size_t)N * 64;          // N*64
    float* dinv = bufB + (size_t)N * 64;          // N
    float* sbuf = dinv + N;                       // N
    float* gbuf = sbuf + N;                       // N
    int*   degi = (int*)(gbuf + N);               // N
    int*   off  = degi + N;                       // N
    int*   curp = off + N;                        // N
    int*   col  = curp + N;                       // E
    int*   bsum = col + E;                        // 1024
    int*   flag = bsum + 1024;                    // 1

    const int BT = 256;
    const int gridN  = cdiv(N, BT);
    const int gridE  = cdiv(E, BT);
    const int gridNd = cdiv(N, 4);
    const int gridDense = 1024;
    const int gridFill  = 8 * 160;
    const int B      = cdiv(N, 1024);

    detect_idx_kernel<<<1, 1, 0, stream>>>(ei, flag);

    // ---- CSR build (once; edges are layer-invariant) ----
    zero_int_kernel<<<gridN, BT, 0, stream>>>(degi, N);
    hist_kernel<<<gridE, BT, 0, stream>>>(ei, flag, degi, E);
    scanA_kernel<<<B, 256, 0, stream>>>(degi, off, bsum, N);
    scanB_kernel<<<1, 1024, 0, stream>>>(bsum, B);
    scanC_kernel<<<gridN, BT, 0, stream>>>(off, bsum, N);
    copy_int_kernel<<<gridN, BT, 0, stream>>>(curp, off, N);
    fill_kernel<<<gridFill, BT, 0, stream>>>(ei, flag, curp, col, E);
    deginv_kernel<<<gridN, BT, 0, stream>>>(degi, dinv, N);

    // ---- layer 1: x -> bufA ----
    gather64_kernel<<<gridNd, BT, 0, stream>>>(x, off, curp, col, dinv, bufA, N);
    dense_reg_kernel<<<gridDense, BT, 0, stream>>>(x, bufA, Ws1, Wn1, b1, bufA, N, 1);

    // ---- layer 2: bufA -> bufB ----
    gather64_kernel<<<gridNd, BT, 0, stream>>>(bufA, off, curp, col, dinv, bufB, N);
    dense_reg_kernel<<<gridDense, BT, 0, stream>>>(bufA, bufB, Ws2, Wn2, b2, bufB, N, 1);

    // ---- layer 3: bufB -> bufA ----
    gather64_kernel<<<gridNd, BT, 0, stream>>>(bufB, off, curp, col, dinv, bufA, N);
    dense_reg_kernel<<<gridDense, BT, 0, stream>>>(bufB, bufA, Ws3, Wn3, b3, bufA, N, 1);

    // ---- layer 4 (64->1): pre-transform then scalar CSR gather + sigmoid ----
    layer4_pre_kernel<<<gridNd, BT, 0, stream>>>(bufA, Ws4, Wn4, sbuf, gbuf, N);
    final_kernel<<<gridN, BT, 0, stream>>>(sbuf, dinv, gbuf, off, curp, col, b4, out, N);
}

// Round 6
// 623.905 us; speedup vs baseline: 1.1357x; 1.1357x over previous
//
#include <hip/hip_runtime.h>
#include <hip/hip_bf16.h>
#include <math.h>

// ---------------------------------------------------------------------------
// ActorGNN: 4-layer GraphConv. R6:
//  - dense: LDS-transposed+padded weights (sW[k*65+lane], 2-way free), 4
//    nodes/wave so each ds_read feeds 8 FMAs; FMA-bound (~10us floor).
//    R4/R5's register-weights scheme was defeated by the allocator (VGPR=72).
//  - gather: bf16 rows (dense epilogue writes an RNE-bf16 copy). R5 gather
//    was byte-bound at ~4.5 TB/s TCC path (410MB/layer = 91us); bf16 halves
//    bytes. Aggregation-only bf16 keeps error ~1e-3 (mean averages it down).
// ---------------------------------------------------------------------------

__device__ __forceinline__ int load_idx32(const int* __restrict__ ei32, int is64,
                                          long long pos) {
    return is64 ? ei32[2 * pos] : ei32[pos];
}

__device__ __forceinline__ unsigned short f2b_rne(float f) {
    union { float f; unsigned u; } c;
    c.f = f;
    unsigned r = c.u + 0x7FFFu + ((c.u >> 16) & 1u);
    return (unsigned short)(r >> 16);
}

__device__ __forceinline__ float b2f(unsigned short u) {
    union { unsigned u; float f; } c;
    c.u = ((unsigned)u) << 16;
    return c.f;
}

// int64 vs int32 edge_index detection (int64 values < 2^31 => odd words zero)
__global__ void detect_idx_kernel(const int* __restrict__ ei, int* __restrict__ flag) {
    int allz = 1;
    for (int i = 0; i < 32; ++i)
        if (ei[2 * i + 1] != 0) allz = 0;
    *flag = allz;
}

__global__ void zero_int_kernel(int* __restrict__ p, int n) {
    int i = blockIdx.x * blockDim.x + threadIdx.x;
    if (i < n) p[i] = 0;
}

__global__ void hist_kernel(const int* __restrict__ ei32, const int* __restrict__ flagp,
                            int* __restrict__ degi, int E) {
    int e = blockIdx.x * blockDim.x + threadIdx.x;
    if (e >= E) return;
    int is64 = *flagp;
    int dst = load_idx32(ei32, is64, (long long)E + e);
    atomicAdd(&degi[dst], 1);
}

// exclusive scan over degi -> off, 1024 elems/block, block sums -> bsum
__global__ __launch_bounds__(256) void scanA_kernel(const int* __restrict__ degi,
                                                    int* __restrict__ off,
                                                    int* __restrict__ bsum, int N) {
    __shared__ int lds[256];
    int t = threadIdx.x;
    int base = blockIdx.x * 1024 + t * 4;
    int d[4];
#pragma unroll
    for (int i = 0; i < 4; ++i) d[i] = (base + i < N) ? degi[base + i] : 0;
    int s = d[0] + d[1] + d[2] + d[3];
    lds[t] = s;
    __syncthreads();
    for (int o = 1; o < 256; o <<= 1) {
        int v = (t >= o) ? lds[t - o] : 0;
        __syncthreads();
        lds[t] += v;
        __syncthreads();
    }
    int excl = lds[t] - s;
    if (t == 255) bsum[blockIdx.x] = lds[255];
    int p = excl;
#pragma unroll
    for (int i = 0; i < 4; ++i) {
        if (base + i < N) off[base + i] = p;
        p += d[i];
    }
}

__global__ __launch_bounds__(1024) void scanB_kernel(int* __restrict__ bsum, int B) {
    __shared__ int lds[1024];
    int t = threadIdx.x;
    int s = (t < B) ? bsum[t] : 0;
    lds[t] = s;
    __syncthreads();
    for (int o = 1; o < 1024; o <<= 1) {
        int v = (t >= o) ? lds[t - o] : 0;
        __syncthreads();
        lds[t] += v;
        __syncthreads();
    }
    if (t < B) bsum[t] = lds[t] - s;
}

__global__ void scanC_kernel(int* __restrict__ off, const int* __restrict__ bsum, int N) {
    int i = blockIdx.x * blockDim.x + threadIdx.x;
    if (i < N) off[i] += bsum[i >> 10];
}

__global__ void copy_int_kernel(int* __restrict__ dstp, const int* __restrict__ srcp, int n) {
    int i = blockIdx.x * blockDim.x + threadIdx.x;
    if (i < n) dstp[i] = srcp[i];
}

// dst-range-partitioned CSR fill (L2 line locality for the scattered writes).
// Afterwards cur[n] == off[n] + deg[n] (used as `end`).
__global__ __launch_bounds__(256) void fill_kernel(const int* __restrict__ ei32,
                                                   const int* __restrict__ flagp,
                                                   int* __restrict__ cur,
                                                   int* __restrict__ col, int E) {
    int r = blockIdx.x & 7;
    int chunk = blockIdx.x >> 3;
    int nchunks = gridDim.x >> 3;
    int is64 = *flagp;
    int stride = nchunks * 256;
    for (int e = chunk * 256 + threadIdx.x; e < E; e += stride) {
        int dst = load_idx32(ei32, is64, (long long)E + e);
        if ((int)(((unsigned)dst * 41u) >> 19) == r) {
            int src = load_idx32(ei32, is64, e);
            int pos = atomicAdd(&cur[dst], 1);
            col[pos] = src;
        }
    }
}

__global__ void deginv_kernel(const int* __restrict__ degi, float* __restrict__ dinv, int N) {
    int n = blockIdx.x * blockDim.x + threadIdx.x;
    if (n < N) dinv[n] = 1.0f / fmaxf((float)degi[n], 1.0f);
}

// fp32 -> bf16(RNE) bulk convert (for x before layer-1 gather)
__global__ void f2b_kernel(const float4* __restrict__ in, ushort4* __restrict__ out,
                           int n4) {
    int i = blockIdx.x * blockDim.x + threadIdx.x;
    if (i >= n4) return;
    float4 v = in[i];
    ushort4 u;
    u.x = f2b_rne(v.x); u.y = f2b_rne(v.y); u.z = f2b_rne(v.z); u.w = f2b_rne(v.w);
    out[i] = u;
}

// wave per node; lane = g*16 + t: edge-group g (0..3), dims t*4..t*4+3.
// bf16 rows (128B): one dwordx2 per lane covers 4 dims of one edge's row.
// Output = dinv[n] * sum (mean aggregation), fp32.
__global__ __launch_bounds__(256) void gather64_b16_kernel(
    const unsigned short* __restrict__ hb, const int* __restrict__ off,
    const int* __restrict__ endp, const int* __restrict__ col,
    const float* __restrict__ dinv, float* __restrict__ agg, int N) {
    int wave = threadIdx.x >> 6;
    int lane = threadIdx.x & 63;
    int g = lane >> 4;
    int t = lane & 15;
    int n = blockIdx.x * 4 + wave;
    if (n >= N) return;
    int e = off[n], end = endp[n];
    float4 a0 = make_float4(0.f, 0.f, 0.f, 0.f);
    float4 a1 = make_float4(0.f, 0.f, 0.f, 0.f);
    float4 a2 = make_float4(0.f, 0.f, 0.f, 0.f);
    float4 a3 = make_float4(0.f, 0.f, 0.f, 0.f);
    for (; e + 16 <= end; e += 16) {
        int s0 = col[e + g];
        int s1 = col[e + 4 + g];
        int s2 = col[e + 8 + g];
        int s3 = col[e + 12 + g];
        ushort4 u0 = *(const ushort4*)&hb[(size_t)s0 * 64 + t * 4];
        ushort4 u1 = *(const ushort4*)&hb[(size_t)s1 * 64 + t * 4];
        ushort4 u2 = *(const ushort4*)&hb[(size_t)s2 * 64 + t * 4];
        ushort4 u3 = *(const ushort4*)&hb[(size_t)s3 * 64 + t * 4];
        a0.x += b2f(u0.x); a0.y += b2f(u0.y); a0.z += b2f(u0.z); a0.w += b2f(u0.w);
        a1.x += b2f(u1.x); a1.y += b2f(u1.y); a1.z += b2f(u1.z); a1.w += b2f(u1.w);
        a2.x += b2f(u2.x); a2.y += b2f(u2.y); a2.z += b2f(u2.z); a2.w += b2f(u2.w);
        a3.x += b2f(u3.x); a3.y += b2f(u3.y); a3.z += b2f(u3.z); a3.w += b2f(u3.w);
    }
    for (; e + 8 <= end; e += 8) {
        int s0 = col[e + g];
        int s1 = col[e + 4 + g];
        ushort4 u0 = *(const ushort4*)&hb[(size_t)s0 * 64 + t * 4];
        ushort4 u1 = *(const ushort4*)&hb[(size_t)s1 * 64 + t * 4];
        a0.x += b2f(u0.x); a0.y += b2f(u0.y); a0.z += b2f(u0.z); a0.w += b2f(u0.w);
        a1.x += b2f(u1.x); a1.y += b2f(u1.y); a1.z += b2f(u1.z); a1.w += b2f(u1.w);
    }
    for (; e < end; e += 4) {
        if (e + g < end) {
            int s0 = col[e + g];
            ushort4 u0 = *(const ushort4*)&hb[(size_t)s0 * 64 + t * 4];
            a2.x += b2f(u0.x); a2.y += b2f(u0.y); a2.z += b2f(u0.z); a2.w += b2f(u0.w);
        }
    }
    float4 acc;
    acc.x = (a0.x + a1.x) + (a2.x + a3.x);
    acc.y = (a0.y + a1.y) + (a2.y + a3.y);
    acc.z = (a0.z + a1.z) + (a2.z + a3.z);
    acc.w = (a0.w + a1.w) + (a2.w + a3.w);
#pragma unroll
    for (int m = 16; m <= 32; m <<= 1) {
        acc.x += __shfl_xor(acc.x, m, 64);
        acc.y += __shfl_xor(acc.y, m, 64);
        acc.z += __shfl_xor(acc.z, m, 64);
        acc.w += __shfl_xor(acc.w, m, 64);
    }
    if (g == 0) {
        float di = dinv[n];
        acc.x *= di; acc.y *= di; acc.z *= di; acc.w *= di;
        ((float4*)agg)[(size_t)n * 16 + t] = acc;
    }
}

// out[n,:] = act(h[n,:]@Ws + agg[n,:]@Wn + b); agg pre-scaled by dinv.
// Weights transposed+padded in LDS (sW[k*65+lane]: 2-way bank alias = free).
// 4 nodes per wave: each ds_read feeds 8 FMAs -> FMA-bound. h/agg rows are
// wave-uniform (readfirstlane) -> scalar-load path. out may alias agg.
// Optionally emits bf16 copy of out (for the next layer's gather).
__global__ __launch_bounds__(256) void dense_lds_kernel(
    const float* __restrict__ h, const float* __restrict__ agg,
    const float* __restrict__ Ws, const float* __restrict__ Wn,
    const float* __restrict__ b, float* __restrict__ out,
    unsigned short* __restrict__ out16, int N, int do_relu) {
    __shared__ float sWs[64 * 65];
    __shared__ float sWn[64 * 65];
    for (int i = threadIdx.x; i < 64 * 64; i += 256) {
        int k = i >> 6, n = i & 63;
        sWs[k * 65 + n] = Ws[i];
        sWn[k * 65 + n] = Wn[i];
    }
    __syncthreads();
    int lane = threadIdx.x & 63;
    int wave = threadIdx.x >> 6;
    float bl = b[lane];
    int ngroups = (N + 3) >> 2;
    int gstride = gridDim.x * 4;
    for (int gi = blockIdx.x * 4 + wave; gi < ngroups; gi += gstride) {
        int n0 = __builtin_amdgcn_readfirstlane(gi << 2);
        if (n0 + 3 < N) {
            const float* h0 = h + (size_t)n0 * 64;
            const float* h1 = h0 + 64;
            const float* h2 = h0 + 128;
            const float* h3 = h0 + 192;
            const float* a0 = agg + (size_t)n0 * 64;
            const float* a1 = a0 + 64;
            const float* a2 = a0 + 128;
            const float* a3 = a0 + 192;
            float c0 = bl, c1 = bl, c2 = bl, c3 = bl;
#pragma unroll
            for (int k = 0; k < 64; ++k) {
                float wsk = sWs[k * 65 + lane];
                float wnk = sWn[k * 65 + lane];
                c0 = fmaf(h0[k], wsk, fmaf(a0[k], wnk, c0));
                c1 = fmaf(h1[k], wsk, fmaf(a1[k], wnk, c1));
                c2 = fmaf(h2[k], wsk, fmaf(a2[k], wnk, c2));
                c3 = fmaf(h3[k], wsk, fmaf(a3[k], wnk, c3));
            }
            if (do_relu) {
                c0 = fmaxf(c0, 0.f); c1 = fmaxf(c1, 0.f);
                c2 = fmaxf(c2, 0.f); c3 = fmaxf(c3, 0.f);
            }
            out[(size_t)n0 * 64 + lane] = c0;
            out[(size_t)(n0 + 1) * 64 + lane] = c1;
            out[(size_t)(n0 + 2) * 64 + lane] = c2;
            out[(size_t)(n0 + 3) * 64 + lane] = c3;
            if (out16) {
                out16[(size_t)n0 * 64 + lane] = f2b_rne(c0);
                out16[(size_t)(n0 + 1) * 64 + lane] = f2b_rne(c1);
                out16[(size_t)(n0 + 2) * 64 + lane] = f2b_rne(c2);
                out16[(size_t)(n0 + 3) * 64 + lane] = f2b_rne(c3);
            }
        } else {
            for (int n = n0; n < N; ++n) {
                const float* hr = h + (size_t)n * 64;
                const float* ar = agg + (size_t)n * 64;
                float c = bl;
                for (int k = 0; k < 64; ++k)
                    c = fmaf(hr[k], sWs[k * 65 + lane], fmaf(ar[k], sWn[k * 65 + lane], c));
                if (do_relu) c = fmaxf(c, 0.f);
                out[(size_t)n * 64 + lane] = c;
                if (out16) out16[(size_t)n * 64 + lane] = f2b_rne(c);
            }
        }
    }
}

// layer-4 pre-transform: s[n]=h[n,:]·Ws4, g[n]=h[n,:]·Wn4 (64->1)
__global__ __launch_bounds__(256) void layer4_pre_kernel(
    const float* __restrict__ h, const float* __restrict__ Ws,
    const float* __restrict__ Wn, float* __restrict__ s, float* __restrict__ g, int N) {
    int wave = threadIdx.x >> 6;
    int lane = threadIdx.x & 63;
    int n = blockIdx.x * 4 + wave;
    if (n >= N) return;
    float hv = h[(size_t)n * 64 + lane];
    float vs = hv * Ws[lane];
    float vn = hv * Wn[lane];
#pragma unroll
    for (int o = 32; o > 0; o >>= 1) {
        vs += __shfl_down(vs, o, 64);
        vn += __shfl_down(vn, o, 64);
    }
    if (lane == 0) {
        s[n] = vs;
        g[n] = vn;
    }
}

// thread per node: scalar CSR gather of g (400 KB, L2-resident) + sigmoid
__global__ void final_kernel(const float* __restrict__ s, const float* __restrict__ dinv,
                             const float* __restrict__ g, const int* __restrict__ off,
                             const int* __restrict__ endp, const int* __restrict__ col,
                             const float* __restrict__ b4, float* __restrict__ out, int N) {
    int n = blockIdx.x * blockDim.x + threadIdx.x;
    if (n >= N) return;
    float a = 0.f;
    int e = off[n], end = endp[n];
    for (; e < end; ++e) a += g[col[e]];
    float z = s[n] + dinv[n] * a + b4[0];
    out[n] = 1.0f / (1.0f + expf(-z));
}

static inline int cdiv(long long a, long long b) { return (int)((a + b - 1) / b); }

extern "C" void kernel_launch(void* const* d_in, const int* in_sizes, int n_in,
                              void* d_out, int out_size, void* d_ws, size_t ws_size,
                              hipStream_t stream) {
    const float* x   = (const float*)d_in[0];
    const int*   ei  = (const int*)d_in[1];
    const float* Ws1 = (const float*)d_in[2];
    const float* Wn1 = (const float*)d_in[3];
    const float* b1  = (const float*)d_in[4];
    const float* Ws2 = (const float*)d_in[5];
    const float* Wn2 = (const float*)d_in[6];
    const float* b2  = (const float*)d_in[7];
    const float* Ws3 = (const float*)d_in[8];
    const float* Wn3 = (const float*)d_in[9];
    const float* b3  = (const float*)d_in[10];
    const float* Ws4 = (const float*)d_in[11];
    const float* Wn4 = (const float*)d_in[12];
    const float* b4  = (const float*)d_in[13];
    float* out = (float*)d_out;

    const int N = in_sizes[0] / 64;
    const int E = in_sizes[1] / 2;

    // workspace layout (floats unless noted)
    float* bufA = (float*)d_ws;                          // N*64
    float* bufB = bufA + (size_t)N * 64;                 // N*64
    float* dinv = bufB + (size_t)N * 64;                 // N
    float* sbuf = dinv + N;                              // N
    float* gbuf = sbuf + N;                              // N
    unsigned short* b16A = (unsigned short*)(gbuf + N);  // N*64 ushort
    unsigned short* b16B = b16A + (size_t)N * 64;        // N*64 ushort
    int*   degi = (int*)(b16B + (size_t)N * 64);         // N
    int*   off  = degi + N;                              // N
    int*   curp = off + N;                               // N
    int*   col  = curp + N;                              // E
    int*   bsum = col + E;                               // 1024
    int*   flag = bsum + 1024;                           // 1

    const int BT = 256;
    const int gridN  = cdiv(N, BT);
    const int gridE  = cdiv(E, BT);
    const int gridNd = cdiv(N, 4);
    const int gridDense = 1024;
    const int gridFill  = 8 * 160;
    const int B      = cdiv(N, 1024);

    detect_idx_kernel<<<1, 1, 0, stream>>>(ei, flag);

    // ---- CSR build (once; edges are layer-invariant) ----
    zero_int_kernel<<<gridN, BT, 0, stream>>>(degi, N);
    hist_kernel<<<gridE, BT, 0, stream>>>(ei, flag, degi, E);
    scanA_kernel<<<B, 256, 0, stream>>>(degi, off, bsum, N);
    scanB_kernel<<<1, 1024, 0, stream>>>(bsum, B);
    scanC_kernel<<<gridN, BT, 0, stream>>>(off, bsum, N);
    copy_int_kernel<<<gridN, BT, 0, stream>>>(curp, off, N);
    fill_kernel<<<gridFill, BT, 0, stream>>>(ei, flag, curp, col, E);
    deginv_kernel<<<gridN, BT, 0, stream>>>(degi, dinv, N);

    // ---- x -> bf16 (for layer-1 gather) ----
    f2b_kernel<<<cdiv((long long)N * 16, BT), BT, 0, stream>>>(
        (const float4*)x, (ushort4*)b16A, N * 16);

    // ---- layer 1: x -> bufA (dense also emits bf16 h1 into b16B) ----
    gather64_b16_kernel<<<gridNd, BT, 0, stream>>>(b16A, off, curp, col, dinv, bufA, N);
    dense_lds_kernel<<<gridDense, BT, 0, stream>>>(x, bufA, Ws1, Wn1, b1, bufA, b16B, N, 1);

    // ---- layer 2: bufA -> bufB (emits bf16 h2 into b16A) ----
    gather64_b16_kernel<<<gridNd, BT, 0, stream>>>(b16B, off, curp, col, dinv, bufB, N);
    dense_lds_kernel<<<gridDense, BT, 0, stream>>>(bufA, bufB, Ws2, Wn2, b2, bufB, b16A, N, 1);

    // ---- layer 3: bufB -> bufA ----
    gather64_b16_kernel<<<gridNd, BT, 0, stream>>>(b16A, off, curp, col, dinv, bufA, N);
    dense_lds_kernel<<<gridDense, BT, 0, stream>>>(bufB, bufA, Ws3, Wn3, b3, bufA,
                                                   (unsigned short*)nullptr, N, 1);

    // ---- layer 4 (64->1): pre-transform then scalar CSR gather + sigmoid ----
    layer4_pre_kernel<<<gridNd, BT, 0, stream>>>(bufA, Ws4, Wn4, sbuf, gbuf, N);
    final_kernel<<<gridN, BT, 0, stream>>>(sbuf, dinv, gbuf, off, curp, col, b4, out, N);
}

// Round 7
// 537.810 us; speedup vs baseline: 1.3175x; 1.1601x over previous
//
#include <hip/hip_runtime.h>
#include <hip/hip_bf16.h>
#include <math.h>

// ---------------------------------------------------------------------------
// ActorGNN: 4-layer GraphConv. R7:
//  - dense: MFMA (16x16x32 bf16) over the concatenated GEMM
//    out = [h | agg*dinv] @ [Ws; Wn] + b, with split-bf16 operands
//    (hi+lo; 3-term product) => fp32-equivalent accuracy at matrix-core
//    speed. R6's fp32-VALU dense was issue/latency-bound at 78us vs 31us
//    FMA floor.
//  - all h state stored as hi/lo bf16 pairs; gather reads hi rows (128B),
//    emits agg hi/lo directly; dense epilogue emits next layer's hi/lo.
// ---------------------------------------------------------------------------

using bfrag = __attribute__((ext_vector_type(8))) short;   // 8 bf16 (4 VGPR)
using ffrag = __attribute__((ext_vector_type(4))) float;   // 4 fp32 acc

__device__ __forceinline__ int load_idx32(const int* __restrict__ ei32, int is64,
                                          long long pos) {
    return is64 ? ei32[2 * pos] : ei32[pos];
}

__device__ __forceinline__ unsigned short f2b_rne(float f) {
    union { float f; unsigned u; } c;
    c.f = f;
    unsigned r = c.u + 0x7FFFu + ((c.u >> 16) & 1u);
    return (unsigned short)(r >> 16);
}

__device__ __forceinline__ float b2f(unsigned short u) {
    union { unsigned u; float f; } c;
    c.u = ((unsigned)u) << 16;
    return c.f;
}

// int64 vs int32 edge_index detection (int64 values < 2^31 => odd words zero)
__global__ void detect_idx_kernel(const int* __restrict__ ei, int* __restrict__ flag) {
    int allz = 1;
    for (int i = 0; i < 32; ++i)
        if (ei[2 * i + 1] != 0) allz = 0;
    *flag = allz;
}

__global__ void zero_int_kernel(int* __restrict__ p, int n) {
    int i = blockIdx.x * blockDim.x + threadIdx.x;
    if (i < n) p[i] = 0;
}

__global__ void hist_kernel(const int* __restrict__ ei32, const int* __restrict__ flagp,
                            int* __restrict__ degi, int E) {
    int e = blockIdx.x * blockDim.x + threadIdx.x;
    if (e >= E) return;
    int is64 = *flagp;
    int dst = load_idx32(ei32, is64, (long long)E + e);
    atomicAdd(&degi[dst], 1);
}

// exclusive scan over degi -> off, 1024 elems/block, block sums -> bsum
__global__ __launch_bounds__(256) void scanA_kernel(const int* __restrict__ degi,
                                                    int* __restrict__ off,
                                                    int* __restrict__ bsum, int N) {
    __shared__ int lds[256];
    int t = threadIdx.x;
    int base = blockIdx.x * 1024 + t * 4;
    int d[4];
#pragma unroll
    for (int i = 0; i < 4; ++i) d[i] = (base + i < N) ? degi[base + i] : 0;
    int s = d[0] + d[1] + d[2] + d[3];
    lds[t] = s;
    __syncthreads();
    for (int o = 1; o < 256; o <<= 1) {
        int v = (t >= o) ? lds[t - o] : 0;
        __syncthreads();
        lds[t] += v;
        __syncthreads();
    }
    int excl = lds[t] - s;
    if (t == 255) bsum[blockIdx.x] = lds[255];
    int p = excl;
#pragma unroll
    for (int i = 0; i < 4; ++i) {
        if (base + i < N) off[base + i] = p;
        p += d[i];
    }
}

__global__ __launch_bounds__(1024) void scanB_kernel(int* __restrict__ bsum, int B) {
    __shared__ int lds[1024];
    int t = threadIdx.x;
    int s = (t < B) ? bsum[t] : 0;
    lds[t] = s;
    __syncthreads();
    for (int o = 1; o < 1024; o <<= 1) {
        int v = (t >= o) ? lds[t - o] : 0;
        __syncthreads();
        lds[t] += v;
        __syncthreads();
    }
    if (t < B) bsum[t] = lds[t] - s;
}

__global__ void scanC_kernel(int* __restrict__ off, const int* __restrict__ bsum, int N) {
    int i = blockIdx.x * blockDim.x + threadIdx.x;
    if (i < N) off[i] += bsum[i >> 10];
}

__global__ void copy_int_kernel(int* __restrict__ dstp, const int* __restrict__ srcp, int n) {
    int i = blockIdx.x * blockDim.x + threadIdx.x;
    if (i < n) dstp[i] = srcp[i];
}

// dst-range-partitioned CSR fill (L2 line locality for the scattered writes).
// Afterwards cur[n] == off[n] + deg[n] (used as `end`).
__global__ __launch_bounds__(256) void fill_kernel(const int* __restrict__ ei32,
                                                   const int* __restrict__ flagp,
                                                   int* __restrict__ cur,
                                                   int* __restrict__ col, int E) {
    int r = blockIdx.x & 7;
    int chunk = blockIdx.x >> 3;
    int nchunks = gridDim.x >> 3;
    int is64 = *flagp;
    int stride = nchunks * 256;
    for (int e = chunk * 256 + threadIdx.x; e < E; e += stride) {
        int dst = load_idx32(ei32, is64, (long long)E + e);
        if ((int)(((unsigned)dst * 41u) >> 19) == r) {
            int src = load_idx32(ei32, is64, e);
            int pos = atomicAdd(&cur[dst], 1);
            col[pos] = src;
        }
    }
}

__global__ void deginv_kernel(const int* __restrict__ degi, float* __restrict__ dinv, int N) {
    int n = blockIdx.x * blockDim.x + threadIdx.x;
    if (n < N) dinv[n] = 1.0f / fmaxf((float)degi[n], 1.0f);
}

// x -> (hi, lo) bf16 split, [n][d] layout preserved
__global__ void split_x_kernel(const float4* __restrict__ in, ushort4* __restrict__ hi,
                               ushort4* __restrict__ lo, int n4) {
    int i = blockIdx.x * blockDim.x + threadIdx.x;
    if (i >= n4) return;
    float4 v = in[i];
    ushort4 h, l;
    h.x = f2b_rne(v.x); l.x = f2b_rne(v.x - b2f(h.x));
    h.y = f2b_rne(v.y); l.y = f2b_rne(v.y - b2f(h.y));
    h.z = f2b_rne(v.z); l.z = f2b_rne(v.z - b2f(h.z));
    h.w = f2b_rne(v.w); l.w = f2b_rne(v.w - b2f(h.w));
    hi[i] = h;
    lo[i] = l;
}

// Build B^T hi/lo for one layer: Bt[n][k], k 0..63 from Ws, 64..127 from Wn.
__global__ void bprep_kernel(const float* __restrict__ Ws, const float* __restrict__ Wn,
                             unsigned short* __restrict__ bthi,
                             unsigned short* __restrict__ btlo) {
    int i = blockIdx.x * blockDim.x + threadIdx.x;
    if (i >= 64 * 128) return;
    int n = i >> 7, k = i & 127;
    float v = (k < 64) ? Ws[k * 64 + n] : Wn[(k - 64) * 64 + n];
    unsigned short hi = f2b_rne(v);
    bthi[i] = hi;
    btlo[i] = f2b_rne(v - b2f(hi));
}

// wave per node; lane = g*16 + t: edge-group g (0..3), dims t*4..t*4+3.
// Reads bf16-hi rows (128B); emits mean-scaled agg as hi/lo bf16 pair.
__global__ __launch_bounds__(256) void gather64_b16_kernel(
    const unsigned short* __restrict__ hb, const int* __restrict__ off,
    const int* __restrict__ endp, const int* __restrict__ col,
    const float* __restrict__ dinv, unsigned short* __restrict__ ghi,
    unsigned short* __restrict__ glo, int N) {
    int wave = threadIdx.x >> 6;
    int lane = threadIdx.x & 63;
    int g = lane >> 4;
    int t = lane & 15;
    int n = blockIdx.x * 4 + wave;
    if (n >= N) return;
    int e = off[n], end = endp[n];
    float4 a0 = make_float4(0.f, 0.f, 0.f, 0.f);
    float4 a1 = make_float4(0.f, 0.f, 0.f, 0.f);
    float4 a2 = make_float4(0.f, 0.f, 0.f, 0.f);
    float4 a3 = make_float4(0.f, 0.f, 0.f, 0.f);
    for (; e + 16 <= end; e += 16) {
        int s0 = col[e + g];
        int s1 = col[e + 4 + g];
        int s2 = col[e + 8 + g];
        int s3 = col[e + 12 + g];
        ushort4 u0 = *(const ushort4*)&hb[(size_t)s0 * 64 + t * 4];
        ushort4 u1 = *(const ushort4*)&hb[(size_t)s1 * 64 + t * 4];
        ushort4 u2 = *(const ushort4*)&hb[(size_t)s2 * 64 + t * 4];
        ushort4 u3 = *(const ushort4*)&hb[(size_t)s3 * 64 + t * 4];
        a0.x += b2f(u0.x); a0.y += b2f(u0.y); a0.z += b2f(u0.z); a0.w += b2f(u0.w);
        a1.x += b2f(u1.x); a1.y += b2f(u1.y); a1.z += b2f(u1.z); a1.w += b2f(u1.w);
        a2.x += b2f(u2.x); a2.y += b2f(u2.y); a2.z += b2f(u2.z); a2.w += b2f(u2.w);
        a3.x += b2f(u3.x); a3.y += b2f(u3.y); a3.z += b2f(u3.z); a3.w += b2f(u3.w);
    }
    for (; e + 8 <= end; e += 8) {
        int s0 = col[e + g];
        int s1 = col[e + 4 + g];
        ushort4 u0 = *(const ushort4*)&hb[(size_t)s0 * 64 + t * 4];
        ushort4 u1 = *(const ushort4*)&hb[(size_t)s1 * 64 + t * 4];
        a0.x += b2f(u0.x); a0.y += b2f(u0.y); a0.z += b2f(u0.z); a0.w += b2f(u0.w);
        a1.x += b2f(u1.x); a1.y += b2f(u1.y); a1.z += b2f(u1.z); a1.w += b2f(u1.w);
    }
    for (; e < end; e += 4) {
        if (e + g < end) {
            int s0 = col[e + g];
            ushort4 u0 = *(const ushort4*)&hb[(size_t)s0 * 64 + t * 4];
            a2.x += b2f(u0.x); a2.y += b2f(u0.y); a2.z += b2f(u0.z); a2.w += b2f(u0.w);
        }
    }
    float4 acc;
    acc.x = (a0.x + a1.x) + (a2.x + a3.x);
    acc.y = (a0.y + a1.y) + (a2.y + a3.y);
    acc.z = (a0.z + a1.z) + (a2.z + a3.z);
    acc.w = (a0.w + a1.w) + (a2.w + a3.w);
#pragma unroll
    for (int m = 16; m <= 32; m <<= 1) {
        acc.x += __shfl_xor(acc.x, m, 64);
        acc.y += __shfl_xor(acc.y, m, 64);
        acc.z += __shfl_xor(acc.z, m, 64);
        acc.w += __shfl_xor(acc.w, m, 64);
    }
    if (g == 0) {
        float di = dinv[n];
        acc.x *= di; acc.y *= di; acc.z *= di; acc.w *= di;
        ushort4 h, l;
        h.x = f2b_rne(acc.x); l.x = f2b_rne(acc.x - b2f(h.x));
        h.y = f2b_rne(acc.y); l.y = f2b_rne(acc.y - b2f(h.y));
        h.z = f2b_rne(acc.z); l.z = f2b_rne(acc.z - b2f(h.z));
        h.w = f2b_rne(acc.w); l.w = f2b_rne(acc.w - b2f(h.w));
        *(ushort4*)&ghi[(size_t)n * 64 + t * 4] = h;
        *(ushort4*)&glo[(size_t)n * 64 + t * 4] = l;
    }
}

// MFMA dense: out = relu([h|agg] @ [Ws;Wn] + b), split-bf16 3-term product.
// Wave handles 16 nodes; A chunks 0-1 from H(hi/lo), 2-3 from G(hi/lo).
// A-frag: m=lane&15, k=quad*8+j. B-frag: n=lane&15, k=quad*8+j (Bt[n][k]).
// C/D: col=lane&15 (out dim), row=quad*4+reg (node). Emits hi/lo bf16.
__global__ __launch_bounds__(256) void dense_mfma_kernel(
    const unsigned short* __restrict__ Hhi, const unsigned short* __restrict__ Hlo,
    const unsigned short* __restrict__ Ghi, const unsigned short* __restrict__ Glo,
    const unsigned short* __restrict__ Bthi, const unsigned short* __restrict__ Btlo,
    const float* __restrict__ b, unsigned short* __restrict__ Dhi,
    unsigned short* __restrict__ Dlo, int N) {
    int lane = threadIdx.x & 63;
    int m = lane & 15, quad = lane >> 4;
    int wid = (blockIdx.x * blockDim.x + threadIdx.x) >> 6;
    int nw = (gridDim.x * blockDim.x) >> 6;
    bfrag bhi[4][4];
#pragma unroll
    for (int t = 0; t < 4; ++t)
#pragma unroll
        for (int c = 0; c < 4; ++c)
            bhi[t][c] = *(const bfrag*)(Bthi + (size_t)(t * 16 + m) * 128 + c * 32 + quad * 8);
    float bl[4];
#pragma unroll
    for (int t = 0; t < 4; ++t) bl[t] = b[t * 16 + m];
    int ngroups = (N + 15) >> 4;
    for (int g = wid; g < ngroups; g += nw) {
        int n0 = g << 4;
        int nr = n0 + m;
        if (nr > N - 1) nr = N - 1;
        const unsigned short* hrow = Hhi + (size_t)nr * 64 + quad * 8;
        const unsigned short* lrow = Hlo + (size_t)nr * 64 + quad * 8;
        const unsigned short* grow = Ghi + (size_t)nr * 64 + quad * 8;
        const unsigned short* wrow = Glo + (size_t)nr * 64 + quad * 8;
        bfrag ah[4], al[4];
        ah[0] = *(const bfrag*)(hrow);
        ah[1] = *(const bfrag*)(hrow + 32);
        ah[2] = *(const bfrag*)(grow);
        ah[3] = *(const bfrag*)(grow + 32);
        al[0] = *(const bfrag*)(lrow);
        al[1] = *(const bfrag*)(lrow + 32);
        al[2] = *(const bfrag*)(wrow);
        al[3] = *(const bfrag*)(wrow + 32);
#pragma unroll
        for (int t = 0; t < 4; ++t) {
            ffrag acc = {bl[t], bl[t], bl[t], bl[t]};
#pragma unroll
            for (int c = 0; c < 4; ++c) {
                bfrag blo = *(const bfrag*)(Btlo + (size_t)(t * 16 + m) * 128 + c * 32 + quad * 8);
                acc = __builtin_amdgcn_mfma_f32_16x16x32_bf16(ah[c], bhi[t][c], acc, 0, 0, 0);
                acc = __builtin_amdgcn_mfma_f32_16x16x32_bf16(al[c], bhi[t][c], acc, 0, 0, 0);
                acc = __builtin_amdgcn_mfma_f32_16x16x32_bf16(ah[c], blo, acc, 0, 0, 0);
            }
#pragma unroll
            for (int r = 0; r < 4; ++r) {
                int node = n0 + quad * 4 + r;
                if (node < N) {
                    float v = fmaxf(acc[r], 0.f);
                    unsigned short hi = f2b_rne(v);
                    Dhi[(size_t)node * 64 + t * 16 + m] = hi;
                    Dlo[(size_t)node * 64 + t * 16 + m] = f2b_rne(v - b2f(hi));
                }
            }
        }
    }
}

// layer-4 pre-transform: s[n]=h[n,:]·Ws4, g[n]=h[n,:]·Wn4 (64->1); h = hi+lo
__global__ __launch_bounds__(256) void layer4_pre_kernel(
    const unsigned short* __restrict__ Hhi, const unsigned short* __restrict__ Hlo,
    const float* __restrict__ Ws, const float* __restrict__ Wn,
    float* __restrict__ s, float* __restrict__ g, int N) {
    int wave = threadIdx.x >> 6;
    int lane = threadIdx.x & 63;
    int n = blockIdx.x * 4 + wave;
    if (n >= N) return;
    float hv = b2f(Hhi[(size_t)n * 64 + lane]) + b2f(Hlo[(size_t)n * 64 + lane]);
    float vs = hv * Ws[lane];
    float vn = hv * Wn[lane];
#pragma unroll
    for (int o = 32; o > 0; o >>= 1) {
        vs += __shfl_down(vs, o, 64);
        vn += __shfl_down(vn, o, 64);
    }
    if (lane == 0) {
        s[n] = vs;
        g[n] = vn;
    }
}

// thread per node: scalar CSR gather of g (400 KB, L2-resident) + sigmoid
__global__ void final_kernel(const float* __restrict__ s, const float* __restrict__ dinv,
                             const float* __restrict__ g, const int* __restrict__ off,
                             const int* __restrict__ endp, const int* __restrict__ col,
                             const float* __restrict__ b4, float* __restrict__ out, int N) {
    int n = blockIdx.x * blockDim.x + threadIdx.x;
    if (n >= N) return;
    float a = 0.f;
    int e = off[n], end = endp[n];
    for (; e < end; ++e) a += g[col[e]];
    float z = s[n] + dinv[n] * a + b4[0];
    out[n] = 1.0f / (1.0f + expf(-z));
}

static inline int cdiv(long long a, long long b) { return (int)((a + b - 1) / b); }

extern "C" void kernel_launch(void* const* d_in, const int* in_sizes, int n_in,
                              void* d_out, int out_size, void* d_ws, size_t ws_size,
                              hipStream_t stream) {
    const float* x   = (const float*)d_in[0];
    const int*   ei  = (const int*)d_in[1];
    const float* Ws1 = (const float*)d_in[2];
    const float* Wn1 = (const float*)d_in[3];
    const float* b1  = (const float*)d_in[4];
    const float* Ws2 = (const float*)d_in[5];
    const float* Wn2 = (const float*)d_in[6];
    const float* b2  = (const float*)d_in[7];
    const float* Ws3 = (const float*)d_in[8];
    const float* Wn3 = (const float*)d_in[9];
    const float* b3  = (const float*)d_in[10];
    const float* Ws4 = (const float*)d_in[11];
    const float* Wn4 = (const float*)d_in[12];
    const float* b4  = (const float*)d_in[13];
    float* out = (float*)d_out;

    const int N = in_sizes[0] / 64;
    const int E = in_sizes[1] / 2;

    // workspace layout
    unsigned short* HhiA = (unsigned short*)d_ws;        // N*64
    unsigned short* HloA = HhiA + (size_t)N * 64;        // N*64
    unsigned short* HhiB = HloA + (size_t)N * 64;        // N*64
    unsigned short* HloB = HhiB + (size_t)N * 64;        // N*64
    unsigned short* Ghi  = HloB + (size_t)N * 64;        // N*64
    unsigned short* Glo  = Ghi + (size_t)N * 64;         // N*64
    unsigned short* Bth  = Glo + (size_t)N * 64;         // 3*8192
    unsigned short* Btl  = Bth + 3 * 8192;               // 3*8192
    float* dinv = (float*)(Btl + 3 * 8192);              // N
    float* sbuf = dinv + N;                              // N
    float* gbuf = sbuf + N;                              // N
    int*   degi = (int*)(gbuf + N);                      // N
    int*   off  = degi + N;                              // N
    int*   curp = off + N;                               // N
    int*   col  = curp + N;                              // E
    int*   bsum = col + E;                               // 1024
    int*   flag = bsum + 1024;                           // 1

    const int BT = 256;
    const int gridN  = cdiv(N, BT);
    const int gridE  = cdiv(E, BT);
    const int gridNd = cdiv(N, 4);
    const int gridMM = cdiv(cdiv(N, 16), 4);  // 4 waves/block, 1 group/wave
    const int gridFill = 8 * 160;
    const int B      = cdiv(N, 1024);

    detect_idx_kernel<<<1, 1, 0, stream>>>(ei, flag);

    // ---- CSR build (once; edges are layer-invariant) ----
    zero_int_kernel<<<gridN, BT, 0, stream>>>(degi, N);
    hist_kernel<<<gridE, BT, 0, stream>>>(ei, flag, degi, E);
    scanA_kernel<<<B, 256, 0, stream>>>(degi, off, bsum, N);
    scanB_kernel<<<1, 1024, 0, stream>>>(bsum, B);
    scanC_kernel<<<gridN, BT, 0, stream>>>(off, bsum, N);
    copy_int_kernel<<<gridN, BT, 0, stream>>>(curp, off, N);
    fill_kernel<<<gridFill, BT, 0, stream>>>(ei, flag, curp, col, E);
    deginv_kernel<<<gridN, BT, 0, stream>>>(degi, dinv, N);

    // ---- weight prep (B^T hi/lo per layer) + x split ----
    bprep_kernel<<<32, BT, 0, stream>>>(Ws1, Wn1, Bth, Btl);
    bprep_kernel<<<32, BT, 0, stream>>>(Ws2, Wn2, Bth + 8192, Btl + 8192);
    bprep_kernel<<<32, BT, 0, stream>>>(Ws3, Wn3, Bth + 16384, Btl + 16384);
    split_x_kernel<<<cdiv((long long)N * 16, BT), BT, 0, stream>>>(
        (const float4*)x, (ushort4*)HhiA, (ushort4*)HloA, N * 16);

    // ---- layer 1: pairA -> pairB ----
    gather64_b16_kernel<<<gridNd, BT, 0, stream>>>(HhiA, off, curp, col, dinv, Ghi, Glo, N);
    dense_mfma_kernel<<<gridMM, BT, 0, stream>>>(HhiA, HloA, Ghi, Glo, Bth, Btl, b1,
                                                 HhiB, HloB, N);

    // ---- layer 2: pairB -> pairA ----
    gather64_b16_kernel<<<gridNd, BT, 0, stream>>>(HhiB, off, curp, col, dinv, Ghi, Glo, N);
    dense_mfma_kernel<<<gridMM, BT, 0, stream>>>(HhiB, HloB, Ghi, Glo, Bth + 8192,
                                                 Btl + 8192, b2, HhiA, HloA, N);

    // ---- layer 3: pairA -> pairB ----
    gather64_b16_kernel<<<gridNd, BT, 0, stream>>>(HhiA, off, curp, col, dinv, Ghi, Glo, N);
    dense_mfma_kernel<<<gridMM, BT, 0, stream>>>(HhiA, HloA, Ghi, Glo, Bth + 16384,
                                                 Btl + 16384, b3, HhiB, HloB, N);

    // ---- layer 4 (64->1): pre-transform then scalar CSR gather + sigmoid ----
    layer4_pre_kernel<<<gridNd, BT, 0, stream>>>(HhiB, HloB, Ws4, Wn4, sbuf, gbuf, N);
    final_kernel<<<gridN, BT, 0, stream>>>(sbuf, dinv, gbuf, off, curp, col, b4, out, N);
}